// Round 1
// baseline (88.186 us; speedup 1.0000x reference)
//
#include <hip/hip_runtime.h>

#define E_ 15000
#define D_ 200
#define L_ 64
#define B_ 256
#define BT 16
#define LOG2E 1.4426950408889634f

// Precompute per-b gathered/transposed operands into workspace:
//   qt[d][b] = emb_e[e1[b],d] * emb_rel[rel[b],d]   (D_ x B_)
//   st[l][b] = lit[e1[b],l] - c[l]                  (L_ x B_)
//   wt[l][b] = nf_weights[rel[b],l]                 (L_ x B_)
//   g[l]     = -log2(e) / var[l]
__global__ __launch_bounds__(256) void setup_k(
    const float* __restrict__ emb_e, const float* __restrict__ emb_rel,
    const float* __restrict__ nfw,   const float* __restrict__ lit,
    const float* __restrict__ c,     const float* __restrict__ var,
    const int* __restrict__ e1,      const int* __restrict__ rel,
    float* __restrict__ qt, float* __restrict__ st,
    float* __restrict__ wt, float* __restrict__ g)
{
    const int b = blockIdx.x;
    const int t = threadIdx.x;
    const int ie = e1[b];
    const int ir = rel[b];
    if (t < D_) qt[t * B_ + b] = emb_e[ie * D_ + t] * emb_rel[ir * D_ + t];
    if (t < L_) {
        st[t * B_ + b] = lit[ie * L_ + t] - c[t];
        wt[t * B_ + b] = nfw[ir * L_ + t];
        if (b == 0) g[t] = -LOG2E / var[t];
    }
}

// lane -> e (coalesced output), BT b's per block held in registers.
// Per-b operands (qt/st/wt/g) are wave-uniform -> scalar loads + SGPR-src VALU.
__global__ __launch_bounds__(256) void main_k(
    const float* __restrict__ emb_e, const float* __restrict__ lit,
    const float* __restrict__ qt,    const float* __restrict__ st,
    const float* __restrict__ wt,    const float* __restrict__ g,
    float* __restrict__ out)
{
    const int e  = blockIdx.x * 256 + threadIdx.x;
    const int ec = (e < E_) ? e : (E_ - 1);   // clamp for loads; stores guarded
    const int b0 = blockIdx.y * BT;

    float acc[BT];
    #pragma unroll
    for (int i = 0; i < BT; ++i) acc[i] = 0.0f;

    // ---- structural score: acc[bb] += emb_e[ec,:] . qt[:, b0+bb] ----
    const float* ee = emb_e + (size_t)ec * D_;
    #pragma unroll 2
    for (int d = 0; d < D_; d += 4) {
        const float4 v4 = *(const float4*)(ee + d);
        const float va[4] = {v4.x, v4.y, v4.z, v4.w};
        #pragma unroll
        for (int k = 0; k < 4; ++k) {
            const float* qr = qt + (d + k) * B_ + b0;
            #pragma unroll
            for (int bb = 0; bb < BT; ++bb)
                acc[bb] = fmaf(va[k], qr[bb], acc[bb]);
        }
    }

    // ---- RBF score: acc[bb] += sum_l exp2(g[l]*(st[l][bb]-x[l])^2) * wt[l][bb] ----
    const float* le = lit + (size_t)ec * L_;
    #pragma unroll 1
    for (int l = 0; l < L_; l += 4) {
        const float4 x4 = *(const float4*)(le + l);
        const float xa[4] = {x4.x, x4.y, x4.z, x4.w};
        #pragma unroll
        for (int k = 0; k < 4; ++k) {
            const float gk = g[l + k];
            const float* sr = st + (l + k) * B_ + b0;
            const float* wr = wt + (l + k) * B_ + b0;
            #pragma unroll
            for (int bb = 0; bb < BT; ++bb) {
                const float t  = sr[bb] - xa[k];
                const float ph = __builtin_amdgcn_exp2f(t * t * gk);
                acc[bb] = fmaf(ph, wr[bb], acc[bb]);
            }
        }
    }

    // ---- sigmoid + store (coalesced along e) ----
    if (e < E_) {
        #pragma unroll
        for (int bb = 0; bb < BT; ++bb) {
            const float z   = acc[bb];
            const float ezn = __builtin_amdgcn_exp2f(-z * LOG2E);
            out[(size_t)(b0 + bb) * E_ + e] = __builtin_amdgcn_rcpf(1.0f + ezn);
        }
    }
}

extern "C" void kernel_launch(void* const* d_in, const int* in_sizes, int n_in,
                              void* d_out, int out_size, void* d_ws, size_t ws_size,
                              hipStream_t stream) {
    const float* emb_e   = (const float*)d_in[0];
    const float* emb_rel = (const float*)d_in[1];
    const float* nfw     = (const float*)d_in[2];
    const float* lit     = (const float*)d_in[3];
    const float* c       = (const float*)d_in[4];
    const float* var     = (const float*)d_in[5];
    const int*   e1      = (const int*)d_in[6];
    const int*   rel     = (const int*)d_in[7];
    float* out = (float*)d_out;

    char* ws = (char*)d_ws;
    float* qt = (float*)(ws);                 // 200*256*4 = 204800 B
    float* st = (float*)(ws + 204800);        // 64*256*4  = 65536 B
    float* wt = (float*)(ws + 270336);        // 64*256*4  = 65536 B
    float* g  = (float*)(ws + 335872);        // 64*4      = 256 B

    setup_k<<<dim3(B_), dim3(256), 0, stream>>>(emb_e, emb_rel, nfw, lit, c, var,
                                                e1, rel, qt, st, wt, g);

    dim3 grid((E_ + 255) / 256, B_ / BT);
    main_k<<<grid, dim3(256), 0, stream>>>(emb_e, lit, qt, st, wt, g, out);
}